// Round 1
// 417.471 us; speedup vs baseline: 1.1529x; 1.1529x over previous
//
#include <hip/hip_runtime.h>
#include <hip/hip_fp16.h>

// Graph_NN: 3-layer SAGE (gcn aggregator), N=100000, E=1600000, D=128, fp32.
// R13 = R12 + bucketed CSR build:
//   k_fill's 84us was NOT a HW ceiling: WRITE_SIZE 101.7MB for 12.8MB payload
//   = one 64B partial-line eviction per 8B write (line siblings arrive from
//   random XCDs -> no L2 combining). Replace atomic scatter with a two-level
//   radix partition by dst-bucket (128 dsts/bucket): hist -> per-bucket
//   block-offset scan -> contiguous per-(block,bucket) scatter into tmp ->
//   per-bucket place (row_ptr built in LDS, eal writes confined to the
//   block's exclusive 16KB window -> full-line evictions from its own L2).
//   Also removes k_count's 1.6M global atomics + memset + bsum/scanb/
//   scan_local chain. tmp aliases hA16, hist/tot alias gB16 (dead until
//   after place). Aggs (3.96TB/s random-gather ceiling) and MFMA GEMMs
//   unchanged from R12.

#define D 128
#define PBLK 128          // partition blocks for hist/scatter
#define BSH 7             // bucket = 128 consecutive dst nodes

typedef float f32x4 __attribute__((ext_vector_type(4)));
typedef _Float16 f16x8 __attribute__((ext_vector_type(8)));

// ---------- bucketed CSR build ----------
__global__ __launch_bounds__(256) void k_hist(
    const int* __restrict__ dst, int* __restrict__ hist,
    int E, int chunk, int nbk) {
    __shared__ int lh[1024];                 // nbk <= 1024
    int j = blockIdx.x, tid = threadIdx.x;
    for (int i = tid; i < nbk; i += 256) lh[i] = 0;
    __syncthreads();
    int e0 = j * chunk, e1 = min(E, e0 + chunk);
    for (int e = e0 + tid; e < e1; e += 256)
        atomicAdd(&lh[dst[e] >> BSH], 1);
    __syncthreads();
    for (int i = tid; i < nbk; i += 256) hist[(size_t)j * nbk + i] = lh[i];
}

// per-bucket exclusive scan over the PBLK block counts; emit bucket totals
__global__ void k_scan_offs(int* __restrict__ hist, int* __restrict__ tot, int nbk) {
    __shared__ int s[PBLK];
    int b = blockIdx.x, j = threadIdx.x;
    int v = hist[(size_t)j * nbk + b];
    s[j] = v;
    __syncthreads();
    for (int off = 1; off < PBLK; off <<= 1) {
        int x = (j >= off) ? s[j - off] : 0;
        __syncthreads();
        s[j] += x;
        __syncthreads();
    }
    hist[(size_t)j * nbk + b] = s[j] - v;    // exclusive within bucket
    if (j == PBLK - 1) tot[b] = s[j];
}

// exclusive scan of bucket totals -> bucket bases; tot[nbk]=E, row_ptr[N]=E
__global__ void k_scan_tot(int* __restrict__ tot, int* __restrict__ row_ptr,
                           int nbk, int N, int E) {
    __shared__ int s[1024];
    int t = threadIdx.x;
    int v = (t < nbk) ? tot[t] : 0;
    s[t] = v;
    __syncthreads();
    for (int off = 1; off < 1024; off <<= 1) {
        int x = (t >= off) ? s[t - off] : 0;
        __syncthreads();
        s[t] += x;
        __syncthreads();
    }
    if (t < nbk) tot[t] = s[t] - v;
    if (t == 0) { tot[nbk] = E; row_ptr[N] = E; }
}

// scatter edges bucket-grouped into tmp: (src, dst_local<<13 | ann[src])
// per-(block,bucket) destination regions are contiguous -> L2 write-combine.
// requires V <= 8192 (ann fits 13 bits); here V = 5000.
__global__ __launch_bounds__(256) void k_scatter(
    const int* __restrict__ src, const int* __restrict__ dst,
    const int* __restrict__ ann, const int* __restrict__ hist,
    const int* __restrict__ tot, int2* __restrict__ tmp,
    int E, int chunk, int nbk) {
    __shared__ int cur[1024];
    int j = blockIdx.x, tid = threadIdx.x;
    for (int i = tid; i < nbk; i += 256)
        cur[i] = tot[i] + hist[(size_t)j * nbk + i];
    __syncthreads();
    int e0 = j * chunk, e1 = min(E, e0 + chunk);
    for (int e = e0 + tid; e < e1; e += 256) {
        int d = dst[e], s = src[e];
        int p = atomicAdd(&cur[d >> BSH], 1);
        tmp[p] = make_int2(s, ((d & ((1 << BSH) - 1)) << 13) | ann[s]);
    }
}

// per-bucket: count per dst in LDS -> row_ptr; place edges into eal.
// all eal writes fall in this block's exclusive [tot[b], tot[b+1]) window.
__global__ __launch_bounds__(256) void k_place(
    const int2* __restrict__ tmp, const int* __restrict__ tot,
    int* __restrict__ row_ptr, int2* __restrict__ eal, int N) {
    __shared__ int cnt[1 << BSH], sc[1 << BSH];
    int b = blockIdx.x, tid = threadIdx.x;
    int base = tot[b], end = tot[b + 1];
    if (tid < (1 << BSH)) cnt[tid] = 0;
    __syncthreads();
    for (int i = base + tid; i < end; i += 256)
        atomicAdd(&cnt[((unsigned)tmp[i].y) >> 13], 1);
    __syncthreads();
    if (tid < (1 << BSH)) sc[tid] = cnt[tid];
    __syncthreads();
    for (int off = 1; off < (1 << BSH); off <<= 1) {
        int x = (tid < (1 << BSH) && tid >= off) ? sc[tid - off] : 0;
        __syncthreads();
        if (tid < (1 << BSH)) sc[tid] += x;
        __syncthreads();
    }
    if (tid < (1 << BSH)) {
        int excl = sc[tid] - cnt[tid];
        int d0 = (b << BSH) + tid;
        if (d0 < N) row_ptr[d0] = base + excl;
        cnt[tid] = excl;                     // becomes the placement cursor
    }
    __syncthreads();
    for (int i = base + tid; i < end; i += 256) {
        int2 w = tmp[i];
        int p = atomicAdd(&cnt[((unsigned)w.y) >> 13], 1);
        eal[base + p] = make_int2(w.x, w.y & 0x1FFF);
    }
}

union H16Chunk { float4 f4; __half2 h2[4]; __half h[8]; };

// ---------- fp32 -> fp16 cast (for emb) ----------
__global__ void k_h16(const float* __restrict__ x, __half* __restrict__ y, int n8) {
    int i = blockIdx.x * blockDim.x + threadIdx.x;
    if (i >= n8) return;
    const float4* p = (const float4*)x;
    float4 a = p[2 * i], b = p[2 * i + 1];
    H16Chunk u;
    u.h2[0] = __floats2half2_rn(a.x, a.y);
    u.h2[1] = __floats2half2_rn(a.z, a.w);
    u.h2[2] = __floats2half2_rn(b.x, b.y);
    u.h2[3] = __floats2half2_rn(b.z, b.w);
    *(float4*)&y[8 * i] = u.f4;
}

// ---------- g16 = x16 @ W via MFMA (fp16 in/out, fp32 W cast to fp16) ------
// 256 thr = 4 waves; wave w owns rows [w*16, w*16+16) of each 64-row tile.
// W staged once per block in B-fragment order; 32 B-frags held in VGPRs.
#define XT_LD 136   // halfs per row: 272B stride -> 16B aligned, conflict-free
__global__ __launch_bounds__(256) void k_gemm_mfma(
    const __half* __restrict__ x16, const float* __restrict__ W,
    __half* __restrict__ g16, int n, int ntiles) {
    __shared__ __half Bf[8 * 4 * 64 * 8];   // 32 KB, fragment order
    __shared__ __half Xt[64 * XT_LD];       // 17 KB, x tile / out stage
    int tid = threadIdx.x;
    int lane = tid & 63;
    int wv = tid >> 6;

    // stage W as fp16 B-fragments: entry (nt,ks,l) holds 8 halfs
    for (int idx = tid; idx < 8 * 4 * 64; idx += 256) {
        int l = idx & 63, ks = (idx >> 6) & 3, nt = idx >> 8;
        int kq = (l >> 4) * 8;
        int col = nt * 16 + (l & 15);
        H16Chunk u;
        #pragma unroll
        for (int j = 0; j < 8; j++)
            u.h[j] = __float2half(W[(ks * 32 + kq + j) * 128 + col]);
        *(float4*)&Bf[idx * 8] = u.f4;
    }
    __syncthreads();

    f16x8 breg[8][4];
    #pragma unroll
    for (int nt = 0; nt < 8; nt++)
        #pragma unroll
        for (int ks = 0; ks < 4; ks++)
            breg[nt][ks] = *(f16x8*)&Bf[((nt * 4 + ks) * 64 + lane) * 8];

    int srow = tid >> 2;            // staging row 0..63
    int sc = (tid & 3) * 32;        // staging col base (halfs)
    int m = lane & 15, quad = lane >> 4;

    for (int tile = blockIdx.x; tile < ntiles; tile += gridDim.x) {
        int row0 = tile * 64;
        __syncthreads();            // Xt free
        {
            int gr = row0 + srow;
            if (gr >= n) gr = n - 1;              // clamp; stores guarded below
            const float4* xp = (const float4*)&x16[(size_t)gr * 128 + sc];
            float4 v0 = xp[0], v1 = xp[1], v2 = xp[2], v3 = xp[3];
            float4* xd = (float4*)&Xt[srow * XT_LD + sc];
            xd[0] = v0; xd[1] = v1; xd[2] = v2; xd[3] = v3;
        }
        __syncthreads();

        f32x4 acc[8];
        #pragma unroll
        for (int nt = 0; nt < 8; nt++) acc[nt] = (f32x4){0.f, 0.f, 0.f, 0.f};
        #pragma unroll
        for (int ks = 0; ks < 4; ks++) {
            f16x8 a = *(f16x8*)&Xt[(wv * 16 + m) * XT_LD + ks * 32 + quad * 8];
            #pragma unroll
            for (int nt = 0; nt < 8; nt++)
                acc[nt] = __builtin_amdgcn_mfma_f32_16x16x32_f16(a, breg[nt][ks], acc[nt], 0, 0, 0);
        }
        __syncthreads();            // done reading Xt; reuse for output
        #pragma unroll
        for (int nt = 0; nt < 8; nt++)
            #pragma unroll
            for (int r = 0; r < 4; r++)
                Xt[(wv * 16 + quad * 4 + r) * XT_LD + nt * 16 + m] = __float2half(acc[nt][r]);
        __syncthreads();
        {
            int gr = row0 + srow;
            if (gr < n) {
                float4* gp = (float4*)&g16[(size_t)gr * 128 + sc];
                float4* xs = (float4*)&Xt[srow * XT_LD + sc];
                gp[0] = xs[0]; gp[1] = xs[1]; gp[2] = xs[2]; gp[3] = xs[3];
            }
        }
    }
}

// ---------- unified agg over fp16 256B rows + fused epilogue ---------------
// SELY: neighbor row = eal.y (ann of src), self row = selfidx[v] (layer 1);
// else neighbor row = eal.x (src),        self row = v        (layers 2-3).
template<bool SELY, bool OUT32>
__global__ __launch_bounds__(256) void k_agg(
    const float4* __restrict__ tab, const int* __restrict__ selfidx,
    const int* __restrict__ row_ptr, const int2* __restrict__ eal,
    const float4* __restrict__ bias4,
    __half* __restrict__ h16out, float* __restrict__ f32out, int n) {
    int v = blockIdx.x * 4 + (threadIdx.x >> 6);
    int lane = threadIdx.x & 63;
    int g = lane >> 4;           // group 0..3
    int q = lane & 15;           // 16B chunk within 256B row
    int beg = row_ptr[v], end = row_ptr[v + 1];
    int deg = end - beg;
    float acc[8] = {};

    #define ACCUM(raw) do { H16Chunk u; u.f4 = (raw);                          \
        float2 t0 = __half22float2(u.h2[0]); acc[0] += t0.x; acc[1] += t0.y;   \
        float2 t1 = __half22float2(u.h2[1]); acc[2] += t1.x; acc[3] += t1.y;   \
        float2 t2 = __half22float2(u.h2[2]); acc[4] += t2.x; acc[5] += t2.y;   \
        float2 t3 = __half22float2(u.h2[3]); acc[6] += t3.x; acc[7] += t3.y; } while (0)
    #define IDX(w) (SELY ? (w).y : (w).x)

    if (g == 0) {
        int sr = SELY ? selfidx[v] : v;
        ACCUM(tab[(size_t)sr * 16 + q]);       // self term once
    }

    int quads = deg >> 2;
    int p = 0;
    for (; p + 4 <= quads; p += 4) {   // deg>=16: 16 rows in flight per wave
        int eb = beg + 4 * p + g;
        int2 w0 = eal[eb + 0], w1 = eal[eb + 4], w2 = eal[eb + 8], w3 = eal[eb + 12];
        float4 r0 = tab[(size_t)IDX(w0) * 16 + q], r1 = tab[(size_t)IDX(w1) * 16 + q];
        float4 r2 = tab[(size_t)IDX(w2) * 16 + q], r3 = tab[(size_t)IDX(w3) * 16 + q];
        ACCUM(r0); ACCUM(r1); ACCUM(r2); ACCUM(r3);
    }
    for (; p < quads; p++) ACCUM(tab[(size_t)IDX(eal[beg + 4 * p + g]) * 16 + q]);
    int tail = deg & 3;
    if (g < tail) ACCUM(tab[(size_t)IDX(eal[beg + 4 * quads + g]) * 16 + q]);
    #undef ACCUM
    #undef IDX

    #pragma unroll
    for (int j = 0; j < 8; j++) {
        acc[j] += __shfl_down(acc[j], 16, 64);   // g0+=g1, g2+=g3
        acc[j] += __shfl_down(acc[j], 32, 64);   // g0+=g2
    }
    if (g == 0) {
        float sc = 1.0f / (float)(deg + 1);
        float4 b0 = bias4[2 * q], b1 = bias4[2 * q + 1];
        float o[8];
        o[0] = fmaxf(acc[0] * sc + b0.x, 0.f);
        o[1] = fmaxf(acc[1] * sc + b0.y, 0.f);
        o[2] = fmaxf(acc[2] * sc + b0.z, 0.f);
        o[3] = fmaxf(acc[3] * sc + b0.w, 0.f);
        o[4] = fmaxf(acc[4] * sc + b1.x, 0.f);
        o[5] = fmaxf(acc[5] * sc + b1.y, 0.f);
        o[6] = fmaxf(acc[6] * sc + b1.z, 0.f);
        o[7] = fmaxf(acc[7] * sc + b1.w, 0.f);
        if (!OUT32) {
            H16Chunk u;
            u.h2[0] = __floats2half2_rn(o[0], o[1]);
            u.h2[1] = __floats2half2_rn(o[2], o[3]);
            u.h2[2] = __floats2half2_rn(o[4], o[5]);
            u.h2[3] = __floats2half2_rn(o[6], o[7]);
            *(float4*)&h16out[(size_t)v * 128 + q * 8] = u.f4;
        } else {
            f32x4 a = {o[0], o[1], o[2], o[3]};
            f32x4 b = {o[4], o[5], o[6], o[7]};
            __builtin_nontemporal_store(a, (f32x4*)&f32out[(size_t)v * 128 + q * 8]);
            __builtin_nontemporal_store(b, (f32x4*)&f32out[(size_t)v * 128 + q * 8 + 4]);
        }
    }
}

extern "C" void kernel_launch(void* const* d_in, const int* in_sizes, int n_in,
                              void* d_out, int out_size, void* d_ws, size_t ws_size,
                              hipStream_t stream) {
    const int*   ann = (const int*)d_in[0];
    const int*   src = (const int*)d_in[1];
    const int*   dst = (const int*)d_in[2];
    const float* emb = (const float*)d_in[3];
    const float* Ws  = (const float*)d_in[4];
    const float* bs  = (const float*)d_in[5];
    float* out = (float*)d_out;

    const int N = in_sizes[0];          // 100000
    const int E = in_sizes[1];          // 1600000
    const int V = in_sizes[3] / D;      // 5000
    const int NT64 = (N + 63) / 64;     // 1563 MFMA row tiles
    const int VT64 = (V + 63) / 64;     // 79
    const int NBK  = (N + (1 << BSH) - 1) >> BSH;   // 782 buckets
    const int CHK  = (E + PBLK - 1) / PBLK;         // 12500 edges/block

    // ws: deg[N] (unused, layout kept) | row_ptr[N+1 pad] | bsum[512 unused]
    //     | eal[int2 E] | hA16[N*D] | gB16[N*D] | embW16[V*D] | emb16[V*D]
    // aliases: tmp (12.8MB) = hA16 (dead until agg1); hist/tot (~400KB)
    //          = gB16 (dead until layer-2 gemm).
    int*  deg     = (int*)d_ws;
    int*  row_ptr = deg + N;
    int*  bsum    = row_ptr + ((N + 1 + 3) & ~3);
    int2* eal     = (int2*)(bsum + 512);
    __half* hA16  = (__half*)(eal + E);
    __half* gB16  = hA16 + (size_t)N * D;
    __half* embW16= gB16 + (size_t)N * D;
    __half* emb16 = embW16 + (size_t)V * D;
    int2* tmp  = (int2*)hA16;
    int*  hist = (int*)gB16;
    int*  tot  = hist + (size_t)PBLK * NBK;

    // --- emb -> fp16; embW16 = emb16 @ W1 (MFMA; independent of CSR) ---
    k_h16<<<(V * D / 8 + 255) / 256, 256, 0, stream>>>(emb, emb16, V * D / 8);
    k_gemm_mfma<<<VT64, 256, 0, stream>>>(emb16, Ws, embW16, V, VT64);

    // --- bucketed CSR build: hist -> offs -> bases -> scatter -> place ---
    k_hist<<<PBLK, 256, 0, stream>>>(dst, hist, E, CHK, NBK);
    k_scan_offs<<<NBK, PBLK, 0, stream>>>(hist, tot, NBK);
    k_scan_tot<<<1, 1024, 0, stream>>>(tot, row_ptr, NBK, N, E);
    k_scatter<<<PBLK, 256, 0, stream>>>(src, dst, ann, hist, tot, tmp, E, CHK, NBK);
    k_place<<<NBK, 256, 0, stream>>>(tmp, tot, row_ptr, eal, N);

    // --- layer 1: fused agg over embW16 (ann-indexed, L2-resident) -> h1 ---
    k_agg<true, false><<<N / 4, 256, 0, stream>>>(
        (const float4*)embW16, ann, row_ptr, eal, (const float4*)bs,
        hA16, nullptr, N);

    // --- layer 2: g1 = h1@W2 (MFMA); fused agg -> h2 (fp16) ---
    k_gemm_mfma<<<512, 256, 0, stream>>>(hA16, Ws + (size_t)D * D, gB16, N, NT64);
    k_agg<false, false><<<N / 4, 256, 0, stream>>>(
        (const float4*)gB16, nullptr, row_ptr, eal, (const float4*)(bs + D),
        hA16, nullptr, N);

    // --- layer 3: g2 = h2@W3 (MFMA); fused agg -> out (fp32, nontemporal) ---
    k_gemm_mfma<<<512, 256, 0, stream>>>(hA16, Ws + (size_t)2 * D * D, gB16, N, NT64);
    k_agg<false, true><<<N / 4, 256, 0, stream>>>(
        (const float4*)gB16, nullptr, row_ptr, eal, (const float4*)(bs + 2 * D),
        nullptr, out, N);
}

// Round 3
// 394.357 us; speedup vs baseline: 1.2204x; 1.0586x over previous
//
#include <hip/hip_runtime.h>
#include <hip/hip_fp16.h>

// Graph_NN: 3-layer SAGE (gcn aggregator), N=100000, E=1600000, D=128, fp32.
// R15 = R14 with the fused-epilogue store bug fixed:
//   R14's k_agg_gemm epilogue stored 1 float4 per thread (8 halfs) at col
//   c*16 with 8 threads/row -> only 64/128 cols written; the other half of
//   g16 kept garbage from the aliased tmp/hist ints (NaN as fp16) -> inf.
//   Fix: store 2 float4s per thread (cols c*16 and c*16+8).
// R14 rationale (unchanged): agg and GEMM commute; h_l had no consumer but
//   the next GEMM, yet cost a 25.6MB write + 25.6MB read per boundary (x2).
//   k_agg_gemm: 64 dsts / 512-thread block; 16-lane unit owns 2 dst rows
//   with full 128-col fp32 acc in regs (no shfl); inv/bias/relu -> fp16
//   h-tile in LDS -> MFMA (W fragments staged per block) -> store g.
//   Bucketed CSR build unchanged from R13.

#define D 128
#define PBLK 128          // partition blocks for hist/scatter
#define BSH 7             // bucket = 128 consecutive dst nodes

typedef float f32x4 __attribute__((ext_vector_type(4)));
typedef _Float16 f16x8 __attribute__((ext_vector_type(8)));

// ---------- bucketed CSR build ----------
__global__ __launch_bounds__(256) void k_hist(
    const int* __restrict__ dst, int* __restrict__ hist,
    int E, int chunk, int nbk) {
    __shared__ int lh[1024];                 // nbk <= 1024
    int j = blockIdx.x, tid = threadIdx.x;
    for (int i = tid; i < nbk; i += 256) lh[i] = 0;
    __syncthreads();
    int e0 = j * chunk, e1 = min(E, e0 + chunk);
    for (int e = e0 + tid; e < e1; e += 256)
        atomicAdd(&lh[dst[e] >> BSH], 1);
    __syncthreads();
    for (int i = tid; i < nbk; i += 256) hist[(size_t)j * nbk + i] = lh[i];
}

// per-bucket exclusive scan over the PBLK block counts; emit bucket totals
__global__ void k_scan_offs(int* __restrict__ hist, int* __restrict__ tot, int nbk) {
    __shared__ int s[PBLK];
    int b = blockIdx.x, j = threadIdx.x;
    int v = hist[(size_t)j * nbk + b];
    s[j] = v;
    __syncthreads();
    for (int off = 1; off < PBLK; off <<= 1) {
        int x = (j >= off) ? s[j - off] : 0;
        __syncthreads();
        s[j] += x;
        __syncthreads();
    }
    hist[(size_t)j * nbk + b] = s[j] - v;    // exclusive within bucket
    if (j == PBLK - 1) tot[b] = s[j];
}

// exclusive scan of bucket totals -> bucket bases; tot[nbk]=E, row_ptr[N]=E
__global__ void k_scan_tot(int* __restrict__ tot, int* __restrict__ row_ptr,
                           int nbk, int N, int E) {
    __shared__ int s[1024];
    int t = threadIdx.x;
    int v = (t < nbk) ? tot[t] : 0;
    s[t] = v;
    __syncthreads();
    for (int off = 1; off < 1024; off <<= 1) {
        int x = (t >= off) ? s[t - off] : 0;
        __syncthreads();
        s[t] += x;
        __syncthreads();
    }
    if (t < nbk) tot[t] = s[t] - v;
    if (t == 0) { tot[nbk] = E; row_ptr[N] = E; }
}

// scatter edges bucket-grouped into tmp: (src, dst_local<<13 | ann[src])
// per-(block,bucket) destination regions are contiguous -> L2 write-combine.
// requires V <= 8192 (ann fits 13 bits); here V = 5000.
__global__ __launch_bounds__(256) void k_scatter(
    const int* __restrict__ src, const int* __restrict__ dst,
    const int* __restrict__ ann, const int* __restrict__ hist,
    const int* __restrict__ tot, int2* __restrict__ tmp,
    int E, int chunk, int nbk) {
    __shared__ int cur[1024];
    int j = blockIdx.x, tid = threadIdx.x;
    for (int i = tid; i < nbk; i += 256)
        cur[i] = tot[i] + hist[(size_t)j * nbk + i];
    __syncthreads();
    int e0 = j * chunk, e1 = min(E, e0 + chunk);
    for (int e = e0 + tid; e < e1; e += 256) {
        int d = dst[e], s = src[e];
        int p = atomicAdd(&cur[d >> BSH], 1);
        tmp[p] = make_int2(s, ((d & ((1 << BSH) - 1)) << 13) | ann[s]);
    }
}

// per-bucket: count per dst in LDS -> row_ptr; place edges into eal.
// all eal writes fall in this block's exclusive [tot[b], tot[b+1]) window.
__global__ __launch_bounds__(256) void k_place(
    const int2* __restrict__ tmp, const int* __restrict__ tot,
    int* __restrict__ row_ptr, int2* __restrict__ eal, int N) {
    __shared__ int cnt[1 << BSH], sc[1 << BSH];
    int b = blockIdx.x, tid = threadIdx.x;
    int base = tot[b], end = tot[b + 1];
    if (tid < (1 << BSH)) cnt[tid] = 0;
    __syncthreads();
    for (int i = base + tid; i < end; i += 256)
        atomicAdd(&cnt[((unsigned)tmp[i].y) >> 13], 1);
    __syncthreads();
    if (tid < (1 << BSH)) sc[tid] = cnt[tid];
    __syncthreads();
    for (int off = 1; off < (1 << BSH); off <<= 1) {
        int x = (tid < (1 << BSH) && tid >= off) ? sc[tid - off] : 0;
        __syncthreads();
        if (tid < (1 << BSH)) sc[tid] += x;
        __syncthreads();
    }
    if (tid < (1 << BSH)) {
        int excl = sc[tid] - cnt[tid];
        int d0 = (b << BSH) + tid;
        if (d0 < N) row_ptr[d0] = base + excl;
        cnt[tid] = excl;                     // becomes the placement cursor
    }
    __syncthreads();
    for (int i = base + tid; i < end; i += 256) {
        int2 w = tmp[i];
        int p = atomicAdd(&cnt[((unsigned)w.y) >> 13], 1);
        eal[base + p] = make_int2(w.x, w.y & 0x1FFF);
    }
}

union H16Chunk { float4 f4; __half2 h2[4]; __half h[8]; };

// ---------- fp32 -> fp16 cast (for emb) ----------
__global__ void k_h16(const float* __restrict__ x, __half* __restrict__ y, int n8) {
    int i = blockIdx.x * blockDim.x + threadIdx.x;
    if (i >= n8) return;
    const float4* p = (const float4*)x;
    float4 a = p[2 * i], b = p[2 * i + 1];
    H16Chunk u;
    u.h2[0] = __floats2half2_rn(a.x, a.y);
    u.h2[1] = __floats2half2_rn(a.z, a.w);
    u.h2[2] = __floats2half2_rn(b.x, b.y);
    u.h2[3] = __floats2half2_rn(b.z, b.w);
    *(float4*)&y[8 * i] = u.f4;
}

// ---------- g16 = x16 @ W via MFMA (fp16 in/out, fp32 W cast to fp16) ------
// Kept for the small V-GEMM (embW16 = emb16 @ W1).
#define XT_LD 136   // halfs per row: 272B stride -> 16B aligned, conflict-free
__global__ __launch_bounds__(256) void k_gemm_mfma(
    const __half* __restrict__ x16, const float* __restrict__ W,
    __half* __restrict__ g16, int n, int ntiles) {
    __shared__ __half Bf[8 * 4 * 64 * 8];   // 32 KB, fragment order
    __shared__ __half Xt[64 * XT_LD];       // 17 KB, x tile / out stage
    int tid = threadIdx.x;
    int lane = tid & 63;
    int wv = tid >> 6;

    for (int idx = tid; idx < 8 * 4 * 64; idx += 256) {
        int l = idx & 63, ks = (idx >> 6) & 3, nt = idx >> 8;
        int kq = (l >> 4) * 8;
        int col = nt * 16 + (l & 15);
        H16Chunk u;
        #pragma unroll
        for (int j = 0; j < 8; j++)
            u.h[j] = __float2half(W[(ks * 32 + kq + j) * 128 + col]);
        *(float4*)&Bf[idx * 8] = u.f4;
    }
    __syncthreads();

    f16x8 breg[8][4];
    #pragma unroll
    for (int nt = 0; nt < 8; nt++)
        #pragma unroll
        for (int ks = 0; ks < 4; ks++)
            breg[nt][ks] = *(f16x8*)&Bf[((nt * 4 + ks) * 64 + lane) * 8];

    int srow = tid >> 2;            // staging row 0..63
    int sc = (tid & 3) * 32;        // staging col base (halfs)
    int m = lane & 15, quad = lane >> 4;

    for (int tile = blockIdx.x; tile < ntiles; tile += gridDim.x) {
        int row0 = tile * 64;
        __syncthreads();            // Xt free
        {
            int gr = row0 + srow;
            if (gr >= n) gr = n - 1;              // clamp; stores guarded below
            const float4* xp = (const float4*)&x16[(size_t)gr * 128 + sc];
            float4 v0 = xp[0], v1 = xp[1], v2 = xp[2], v3 = xp[3];
            float4* xd = (float4*)&Xt[srow * XT_LD + sc];
            xd[0] = v0; xd[1] = v1; xd[2] = v2; xd[3] = v3;
        }
        __syncthreads();

        f32x4 acc[8];
        #pragma unroll
        for (int nt = 0; nt < 8; nt++) acc[nt] = (f32x4){0.f, 0.f, 0.f, 0.f};
        #pragma unroll
        for (int ks = 0; ks < 4; ks++) {
            f16x8 a = *(f16x8*)&Xt[(wv * 16 + m) * XT_LD + ks * 32 + quad * 8];
            #pragma unroll
            for (int nt = 0; nt < 8; nt++)
                acc[nt] = __builtin_amdgcn_mfma_f32_16x16x32_f16(a, breg[nt][ks], acc[nt], 0, 0, 0);
        }
        __syncthreads();            // done reading Xt; reuse for output
        #pragma unroll
        for (int nt = 0; nt < 8; nt++)
            #pragma unroll
            for (int r = 0; r < 4; r++)
                Xt[(wv * 16 + quad * 4 + r) * XT_LD + nt * 16 + m] = __float2half(acc[nt][r]);
        __syncthreads();
        {
            int gr = row0 + srow;
            if (gr < n) {
                float4* gp = (float4*)&g16[(size_t)gr * 128 + sc];
                float4* xs = (float4*)&Xt[srow * XT_LD + sc];
                gp[0] = xs[0]; gp[1] = xs[1]; gp[2] = xs[2]; gp[3] = xs[3];
            }
        }
    }
}

// ---------- fused agg_l + gemm_{l+1}: g = relu((self+sum)*inv + b) @ W ----
// 512 thr = 8 waves = 32 16-lane units; unit u owns dst rows {2u, 2u+1} of
// the 64-row tile. Lane ul holds cols [ul*8, ul*8+8) fp32 in regs (no shfl
// reduce). After gather: inv/bias/relu -> fp16 h-tile in Xt -> MFMA with W
// fragments (Bf, staged once per block) -> transpose-stage -> store g.
template<bool SELY>
__global__ __launch_bounds__(512) void k_agg_gemm(
    const float4* __restrict__ tab, const int* __restrict__ selfidx,
    const int* __restrict__ row_ptr, const int2* __restrict__ eal,
    const float4* __restrict__ bias4, const float* __restrict__ W,
    __half* __restrict__ g16, int n, int ntiles) {
    __shared__ __half Bf[8 * 4 * 64 * 8];   // 32 KB, W fragments
    __shared__ __half Xt[64 * XT_LD];       // 17 KB, h tile / out stage
    int tid = threadIdx.x;
    int lane = tid & 63;
    int wv = tid >> 6;          // 0..7
    int unit = tid >> 4;        // 0..31
    int ul = tid & 15;          // lane within unit = 16B chunk index

    // stage W as fp16 B-fragments
    for (int idx = tid; idx < 8 * 4 * 64; idx += 512) {
        int l = idx & 63, ks = (idx >> 6) & 3, nt = idx >> 8;
        int kq = (l >> 4) * 8;
        int col = nt * 16 + (l & 15);
        H16Chunk u;
        #pragma unroll
        for (int j = 0; j < 8; j++)
            u.h[j] = __float2half(W[(ks * 32 + kq + j) * 128 + col]);
        *(float4*)&Bf[idx * 8] = u.f4;
    }
    __syncthreads();

    int m = lane & 15, quad = lane >> 4;
    int stripe = wv >> 1;             // rows [stripe*16, +16)
    int ntb = (wv & 1) * 4;           // nt half

    #define ACCUMK(A, raw) do { H16Chunk u; u.f4 = (raw);                      \
        float2 t0 = __half22float2(u.h2[0]); A[0] += t0.x; A[1] += t0.y;       \
        float2 t1 = __half22float2(u.h2[1]); A[2] += t1.x; A[3] += t1.y;       \
        float2 t2 = __half22float2(u.h2[2]); A[4] += t2.x; A[5] += t2.y;       \
        float2 t3 = __half22float2(u.h2[3]); A[6] += t3.x; A[7] += t3.y; } while (0)
    #define IDX(w) (SELY ? (w).y : (w).x)

    for (int tile = blockIdx.x; tile < ntiles; tile += gridDim.x) {
        int row0 = tile * 64;
        float acc[2][8] = {};
        int degk[2];
        #pragma unroll
        for (int k = 0; k < 2; k++) {
            int r = unit * 2 + k;
            int v = row0 + r;
            int vv = (v < n) ? v : 0;
            int beg = row_ptr[vv];
            int end = (v < n) ? row_ptr[vv + 1] : beg;
            degk[k] = end - beg;
            int sr = SELY ? selfidx[vv] : vv;
            ACCUMK(acc[k], tab[(size_t)sr * 16 + ul]);       // self term
            int p = beg;
            for (; p + 4 <= end; p += 4) {                   // 4 rows in flight
                int2 w0 = eal[p], w1 = eal[p + 1], w2 = eal[p + 2], w3 = eal[p + 3];
                float4 r0 = tab[(size_t)IDX(w0) * 16 + ul];
                float4 r1 = tab[(size_t)IDX(w1) * 16 + ul];
                float4 r2 = tab[(size_t)IDX(w2) * 16 + ul];
                float4 r3 = tab[(size_t)IDX(w3) * 16 + ul];
                ACCUMK(acc[k], r0); ACCUMK(acc[k], r1);
                ACCUMK(acc[k], r2); ACCUMK(acc[k], r3);
            }
            for (; p < end; p++) ACCUMK(acc[k], tab[(size_t)IDX(eal[p]) * 16 + ul]);
        }
        __syncthreads();            // prev tile's store done reading Xt
        {
            float4 b0 = bias4[2 * ul], b1 = bias4[2 * ul + 1];
            #pragma unroll
            for (int k = 0; k < 2; k++) {
                int r = unit * 2 + k;
                float sc = 1.0f / (float)(degk[k] + 1);
                H16Chunk u;
                u.h2[0] = __floats2half2_rn(fmaxf(acc[k][0] * sc + b0.x, 0.f),
                                            fmaxf(acc[k][1] * sc + b0.y, 0.f));
                u.h2[1] = __floats2half2_rn(fmaxf(acc[k][2] * sc + b0.z, 0.f),
                                            fmaxf(acc[k][3] * sc + b0.w, 0.f));
                u.h2[2] = __floats2half2_rn(fmaxf(acc[k][4] * sc + b1.x, 0.f),
                                            fmaxf(acc[k][5] * sc + b1.y, 0.f));
                u.h2[3] = __floats2half2_rn(fmaxf(acc[k][6] * sc + b1.z, 0.f),
                                            fmaxf(acc[k][7] * sc + b1.w, 0.f));
                *(float4*)&Xt[r * XT_LD + ul * 8] = u.f4;
            }
        }
        __syncthreads();
        f32x4 cacc[4];
        #pragma unroll
        for (int t = 0; t < 4; t++) cacc[t] = (f32x4){0.f, 0.f, 0.f, 0.f};
        #pragma unroll
        for (int ks = 0; ks < 4; ks++) {
            f16x8 a = *(f16x8*)&Xt[(stripe * 16 + m) * XT_LD + ks * 32 + quad * 8];
            #pragma unroll
            for (int t = 0; t < 4; t++) {
                f16x8 b = *(f16x8*)&Bf[(((ntb + t) * 4 + ks) * 64 + lane) * 8];
                cacc[t] = __builtin_amdgcn_mfma_f32_16x16x32_f16(a, b, cacc[t], 0, 0, 0);
            }
        }
        __syncthreads();            // done reading Xt; reuse for output
        #pragma unroll
        for (int t = 0; t < 4; t++)
            #pragma unroll
            for (int r4 = 0; r4 < 4; r4++)
                Xt[(stripe * 16 + quad * 4 + r4) * XT_LD + (ntb + t) * 16 + m] =
                    __float2half(cacc[t][r4]);
        __syncthreads();
        {
            // 512 thr: 8 thr/row x 16 halfs (2 float4s) = 128 cols  (R14 bug:
            // stored only 1 float4 -> half of g16 kept aliased garbage -> inf)
            int srow = tid >> 3, c = tid & 7;
            int gr = row0 + srow;
            float4 v0 = *(float4*)&Xt[srow * XT_LD + c * 16];
            float4 v1 = *(float4*)&Xt[srow * XT_LD + c * 16 + 8];
            if (gr < n) {
                float4* gp = (float4*)&g16[(size_t)gr * 128 + c * 16];
                gp[0] = v0;
                gp[1] = v1;
            }
        }
    }
    #undef ACCUMK
    #undef IDX
}

// ---------- final-layer agg (fp32 out, no following GEMM) ------------------
template<bool SELY, bool OUT32>
__global__ __launch_bounds__(256) void k_agg(
    const float4* __restrict__ tab, const int* __restrict__ selfidx,
    const int* __restrict__ row_ptr, const int2* __restrict__ eal,
    const float4* __restrict__ bias4,
    __half* __restrict__ h16out, float* __restrict__ f32out, int n) {
    int v = blockIdx.x * 4 + (threadIdx.x >> 6);
    int lane = threadIdx.x & 63;
    int g = lane >> 4;           // group 0..3
    int q = lane & 15;           // 16B chunk within 256B row
    int beg = row_ptr[v], end = row_ptr[v + 1];
    int deg = end - beg;
    float acc[8] = {};

    #define ACCUM(raw) do { H16Chunk u; u.f4 = (raw);                          \
        float2 t0 = __half22float2(u.h2[0]); acc[0] += t0.x; acc[1] += t0.y;   \
        float2 t1 = __half22float2(u.h2[1]); acc[2] += t1.x; acc[3] += t1.y;   \
        float2 t2 = __half22float2(u.h2[2]); acc[4] += t2.x; acc[5] += t2.y;   \
        float2 t3 = __half22float2(u.h2[3]); acc[6] += t3.x; acc[7] += t3.y; } while (0)
    #define IDX(w) (SELY ? (w).y : (w).x)

    if (g == 0) {
        int sr = SELY ? selfidx[v] : v;
        ACCUM(tab[(size_t)sr * 16 + q]);       // self term once
    }

    int quads = deg >> 2;
    int p = 0;
    for (; p + 4 <= quads; p += 4) {   // deg>=16: 16 rows in flight per wave
        int eb = beg + 4 * p + g;
        int2 w0 = eal[eb + 0], w1 = eal[eb + 4], w2 = eal[eb + 8], w3 = eal[eb + 12];
        float4 r0 = tab[(size_t)IDX(w0) * 16 + q], r1 = tab[(size_t)IDX(w1) * 16 + q];
        float4 r2 = tab[(size_t)IDX(w2) * 16 + q], r3 = tab[(size_t)IDX(w3) * 16 + q];
        ACCUM(r0); ACCUM(r1); ACCUM(r2); ACCUM(r3);
    }
    for (; p < quads; p++) ACCUM(tab[(size_t)IDX(eal[beg + 4 * p + g]) * 16 + q]);
    int tail = deg & 3;
    if (g < tail) ACCUM(tab[(size_t)IDX(eal[beg + 4 * quads + g]) * 16 + q]);
    #undef ACCUM
    #undef IDX

    #pragma unroll
    for (int j = 0; j < 8; j++) {
        acc[j] += __shfl_down(acc[j], 16, 64);   // g0+=g1, g2+=g3
        acc[j] += __shfl_down(acc[j], 32, 64);   // g0+=g2
    }
    if (g == 0) {
        float sc = 1.0f / (float)(deg + 1);
        float4 b0 = bias4[2 * q], b1 = bias4[2 * q + 1];
        float o[8];
        o[0] = fmaxf(acc[0] * sc + b0.x, 0.f);
        o[1] = fmaxf(acc[1] * sc + b0.y, 0.f);
        o[2] = fmaxf(acc[2] * sc + b0.z, 0.f);
        o[3] = fmaxf(acc[3] * sc + b0.w, 0.f);
        o[4] = fmaxf(acc[4] * sc + b1.x, 0.f);
        o[5] = fmaxf(acc[5] * sc + b1.y, 0.f);
        o[6] = fmaxf(acc[6] * sc + b1.z, 0.f);
        o[7] = fmaxf(acc[7] * sc + b1.w, 0.f);
        if (!OUT32) {
            H16Chunk u;
            u.h2[0] = __floats2half2_rn(o[0], o[1]);
            u.h2[1] = __floats2half2_rn(o[2], o[3]);
            u.h2[2] = __floats2half2_rn(o[4], o[5]);
            u.h2[3] = __floats2half2_rn(o[6], o[7]);
            *(float4*)&h16out[(size_t)v * 128 + q * 8] = u.f4;
        } else {
            f32x4 a = {o[0], o[1], o[2], o[3]};
            f32x4 b = {o[4], o[5], o[6], o[7]};
            __builtin_nontemporal_store(a, (f32x4*)&f32out[(size_t)v * 128 + q * 8]);
            __builtin_nontemporal_store(b, (f32x4*)&f32out[(size_t)v * 128 + q * 8 + 4]);
        }
    }
}

extern "C" void kernel_launch(void* const* d_in, const int* in_sizes, int n_in,
                              void* d_out, int out_size, void* d_ws, size_t ws_size,
                              hipStream_t stream) {
    const int*   ann = (const int*)d_in[0];
    const int*   src = (const int*)d_in[1];
    const int*   dst = (const int*)d_in[2];
    const float* emb = (const float*)d_in[3];
    const float* Ws  = (const float*)d_in[4];
    const float* bs  = (const float*)d_in[5];
    float* out = (float*)d_out;

    const int N = in_sizes[0];          // 100000
    const int E = in_sizes[1];          // 1600000
    const int V = in_sizes[3] / D;      // 5000
    const int NT64 = (N + 63) / 64;     // 1563 MFMA row tiles
    const int VT64 = (V + 63) / 64;     // 79
    const int NBK  = (N + (1 << BSH) - 1) >> BSH;   // 782 buckets
    const int CHK  = (E + PBLK - 1) / PBLK;         // 12500 edges/block

    // ws: deg[N] (unused, layout kept) | row_ptr[N+1 pad] | bsum[512 unused]
    //     | eal[int2 E] | hA16[N*D] | gB16[N*D] | embW16[V*D] | emb16[V*D]
    // aliases: tmp (12.8MB) = hA16 (dead until fused2 writes it); hist/tot
    //          (~400KB) = gB16 (dead until fused1 writes it).
    int*  deg     = (int*)d_ws;
    int*  row_ptr = deg + N;
    int*  bsum    = row_ptr + ((N + 1 + 3) & ~3);
    int2* eal     = (int2*)(bsum + 512);
    __half* hA16  = (__half*)(eal + E);
    __half* gB16  = hA16 + (size_t)N * D;
    __half* embW16= gB16 + (size_t)N * D;
    __half* emb16 = embW16 + (size_t)V * D;
    int2* tmp  = (int2*)hA16;
    int*  hist = (int*)gB16;
    int*  tot  = hist + (size_t)PBLK * NBK;

    // --- emb -> fp16; embW16 = emb16 @ W1 (MFMA; independent of CSR) ---
    k_h16<<<(V * D / 8 + 255) / 256, 256, 0, stream>>>(emb, emb16, V * D / 8);
    k_gemm_mfma<<<VT64, 256, 0, stream>>>(emb16, Ws, embW16, V, VT64);

    // --- bucketed CSR build: hist -> offs -> bases -> scatter -> place ---
    k_hist<<<PBLK, 256, 0, stream>>>(dst, hist, E, CHK, NBK);
    k_scan_offs<<<NBK, PBLK, 0, stream>>>(hist, tot, NBK);
    k_scan_tot<<<1, 1024, 0, stream>>>(tot, row_ptr, NBK, N, E);
    k_scatter<<<PBLK, 256, 0, stream>>>(src, dst, ann, hist, tot, tmp, E, CHK, NBK);
    k_place<<<NBK, 256, 0, stream>>>(tmp, tot, row_ptr, eal, N);

    // --- layer 1 agg (embW16, ann-indexed) fused with g2 = h1@W2 -> gB16 ---
    k_agg_gemm<true><<<NT64, 512, 0, stream>>>(
        (const float4*)embW16, ann, row_ptr, eal, (const float4*)bs,
        Ws + (size_t)D * D, gB16, N, NT64);

    // --- layer 2 agg (gB16) fused with g3 = h2@W3 -> hA16 ---
    k_agg_gemm<false><<<NT64, 512, 0, stream>>>(
        (const float4*)gB16, nullptr, row_ptr, eal, (const float4*)(bs + D),
        Ws + (size_t)2 * D * D, hA16, N, NT64);

    // --- layer 3: agg over g3 -> out (fp32, nontemporal) ---
    k_agg<false, true><<<N / 4, 256, 0, stream>>>(
        (const float4*)hA16, nullptr, row_ptr, eal, (const float4*)(bs + 2 * D),
        nullptr, out, N);
}